// Round 8
// baseline (227.128 us; speedup 1.0000x reference)
//
#pragma clang fp contract(off)
#include <hip/hip_runtime.h>
#include <hip/hip_bf16.h>
#include <hip/hip_cooperative_groups.h>

namespace cg = cooperative_groups;

typedef unsigned long long u64;
typedef unsigned int u32;

#define NPTS   200000
#define MBOX   128
#define W64    3125      // NPTS / 64 exactly
#define W64C   3200      // padded row stride (u64 words)
#define SSAMP  256
#define AANCH  3
#define VOXELF 0.4f
#define PCSF   -75.2f
#define TILEW  9.375f    // 150/16
#define NB     256
#define BS     256
#define GT     (NB*BS)   // 65536 threads
#define ZU4    208896    // (128*3200*8 + 65536) / 16 bytes of zero region

__global__ __launch_bounds__(256) void fused(
    const float* __restrict__ points,
    const float* __restrict__ boxes,
    const int*   __restrict__ labels,
    const int*   __restrict__ pNA,
    u64*  __restrict__ rowbits,
    u32*  __restrict__ inter,
    float* __restrict__ bpk,
    u64*  __restrict__ tmask,
    int*  __restrict__ aidx,
    float* __restrict__ out,
    float* __restrict__ out_anchor)
{
    cg::grid_group grid = cg::this_grid();
    int tid = threadIdx.x, bid = blockIdx.x;
    int gtid = bid * BS + tid;
    int lane = tid & 63, wv = tid >> 6;

    __shared__ float4 sB4[128];   // {bx,by,r,qx}
    __shared__ float2 sB2[128];   // {qy,rv}
    __shared__ u64   sTM[512];
    __shared__ float sMax[128];
    __shared__ int   sMidx[128];
    __shared__ u32   scnt[128];
    __shared__ int   slab[128];
    __shared__ int   sA[384];
    __shared__ u32   sl3[256], sl2[256], sl1[256];
    __shared__ u64   swt[4];

    // ================= P0: zero rowbits+inter; block 0 precomputes bpk/tmask =================
    {
        uint4* z = (uint4*)rowbits;            // rowbits and inter are contiguous in ws
        for (int idx = gtid; idx < ZU4; idx += GT) z[idx] = make_uint4(0, 0, 0, 0);
        if (bid == 0) {
            __shared__ float sbx[128], sby[128], srch[128];
            if (tid < 128) {
                float bx = boxes[tid*7+0], by = boxes[tid*7+1];
                float dx = boxes[tid*7+3], dy = boxes[tid*7+4];
                float hx = dx * 0.5f, hy = dy * 0.5f;
                float sq = hx*hx;
                sq = sq + hy*hy;
                float r = sqrtf(sq);                         // radii (GAMMA=1)
                float qx = floorf((bx - PCSF) / VOXELF);
                float qy = floorf((by - PCSF) / VOXELF);
                float rv = ceilf(r / VOXELF);                // rad_vox
                bpk[tid*8+0] = bx; bpk[tid*8+1] = by; bpk[tid*8+2] = r;  bpk[tid*8+3] = qx;
                bpk[tid*8+4] = qy; bpk[tid*8+5] = rv; bpk[tid*8+6] = 0.f; bpk[tid*8+7] = 0.f;
                sbx[tid] = bx; sby[tid] = by;
                srch[tid] = VOXELF * (rv + 2.0f);            // conservative reach (>=0.8m slack)
            }
            __syncthreads();
            int tx = tid & 15, ty = tid >> 4;
            float x0 = -75.0f + tx * TILEW, x1 = x0 + TILEW;
            float y0 = -75.0f + ty * TILEW, y1 = y0 + TILEW;
            u64 m0 = 0, m1 = 0;
            for (int m = 0; m < 128; ++m) {
                float rc = srch[m];
                bool c = (sbx[m] > x0 - rc) & (sbx[m] < x1 + rc) &
                         (sby[m] > y0 - rc) & (sby[m] < y1 + rc);
                if (m < 64) m0 |= ((u64)c) << m;
                else        m1 |= ((u64)c) << (m - 64);
            }
            tmask[tid*2]   = m0;
            tmask[tid*2+1] = m1;
        }
    }
    __threadfence();
    grid.sync();

    // ================= P1: tile-pruned point pass (atomicOr rowbits, atomicAdd inter) ========
    {
        if (tid < 128) {
            const float4* bp = (const float4*)bpk;
            float4 a = bp[tid*2];
            float4 b = bp[tid*2+1];
            sB4[tid] = a;
            sB2[tid] = make_float2(b.x, b.y);
        }
        sTM[tid]       = tmask[tid];
        sTM[tid + 256] = tmask[tid + 256];
        __syncthreads();
        for (int n = gtid; n < NPTS; n += GT) {
            float px = points[n*5+0], py = points[n*5+1];
            float cxn = floorf((px - PCSF) / VOXELF);
            float cyn = floorf((py - PCSF) / VOXELF);
            int tx = (int)floorf((px + 75.0f) * (1.0f / TILEW));
            int ty = (int)floorf((py + 75.0f) * (1.0f / TILEW));
            tx = tx < 0 ? 0 : (tx > 15 ? 15 : tx);
            ty = ty < 0 ? 0 : (ty > 15 ? 15 : ty);
            int tile = ty * 16 + tx;
            u64 c0 = sTM[tile*2], c1 = sTM[tile*2+1];
            u64 h0 = 0, h1 = 0;
            bool voxany = false;
            while (c0) {
                int m = __builtin_ctzll(c0); c0 &= c0 - 1;
                float4 bd = sB4[m]; float2 be = sB2[m];
                float ddx = px - bd.x, ddy = py - bd.y;
                float sq = ddx*ddx;
                sq = sq + ddy*ddy;
                float dis = sqrtf(sq);
                bool hit = (dis <= bd.z);
                bool vox = (fabsf(bd.w - cxn) < be.y) & (fabsf(be.x - cyn) < be.y);
                voxany |= vox;
                h0 |= ((u64)hit) << m;
            }
            while (c1) {
                int m = __builtin_ctzll(c1); c1 &= c1 - 1;
                float4 bd = sB4[m + 64]; float2 be = sB2[m + 64];
                float ddx = px - bd.x, ddy = py - bd.y;
                float sq = ddx*ddx;
                sq = sq + ddy*ddy;
                float dis = sqrtf(sq);
                bool hit = (dis <= bd.z);
                bool vox = (fabsf(bd.w - cxn) < be.y) & (fabsf(be.x - cyn) < be.y);
                voxany |= vox;
                h1 |= ((u64)hit) << m;
            }
            if (!voxany) { h0 = 0; h1 = 0; }   // point_mask = circle & vmask
            if ((h0 | h1) == 0) continue;

            int w = n >> 6, ln = n & 63;
            u64 lanebit = 1ull << ln;
            u64 e = h0;
            while (e) {
                int m = __builtin_ctzll(e); e &= e - 1;
                atomicOr(&rowbits[(size_t)m * W64C + w], lanebit);
                u64 f = h0;
                while (f) { int j = __builtin_ctzll(f); f &= f - 1; atomicAdd(&inter[m*128 + j], 1u); }
                f = h1;
                while (f) { int j = __builtin_ctzll(f); f &= f - 1; atomicAdd(&inter[m*128 + 64 + j], 1u); }
            }
            e = h1;
            while (e) {
                int m = __builtin_ctzll(e); e &= e - 1;
                atomicOr(&rowbits[(size_t)(m + 64) * W64C + w], lanebit);
                u64 f = h0;
                while (f) { int j = __builtin_ctzll(f); f &= f - 1; atomicAdd(&inter[(m+64)*128 + j], 1u); }
                f = h1;
                while (f) { int j = __builtin_ctzll(f); f &= f - 1; atomicAdd(&inter[(m+64)*128 + 64 + j], 1u); }
            }
        }
    }
    __threadfence();
    grid.sync();

    // ================= P2: block 0 — argmax (4 waves x 32 rows) + packed greedy scan =========
    if (bid == 0) {
        if (tid < 128) {
            scnt[tid] = inter[tid * 128 + tid];
            slab[tid] = labels[tid];
            sA[tid] = -1; sA[tid + 128] = -1; sA[tid + 256] = -1;
        }
        __syncthreads();
        for (int t = 0; t < 32; ++t) {
            int i = wv * 32 + t;
            u32 ci = scnt[i];
            int li = slab[i];
            u32 I1 = inter[i * 128 + lane];
            u32 I2 = inter[i * 128 + 64 + lane];
            int j1 = lane, j2 = lane + 64;
            long un1 = (long)ci + (long)scnt[j1] - (long)I1;
            long un2 = (long)ci + (long)scnt[j2] - (long)I2;
            float v1 = 0.0f, v2 = 0.0f;
            if ((j1 != i) && (slab[j1] == li) && (un1 > 0))
                v1 = (float)I1 / fmaxf((float)un1, 1.0f);
            if ((j2 != i) && (slab[j2] == li) && (un2 > 0))
                v2 = (float)I2 / fmaxf((float)un2, 1.0f);
            u64 k1 = ((u64)__float_as_uint(v1) << 32) | (u32)(127 - j1);
            u64 k2 = ((u64)__float_as_uint(v2) << 32) | (u32)(127 - j2);
            u64 key = (k1 > k2) ? k1 : k2;
            #pragma unroll
            for (int d = 1; d < 64; d <<= 1) {
                u64 o = __shfl_xor(key, d);
                key = (key > o) ? key : o;
            }
            if (lane == 0) {
                sMax[i]  = __uint_as_float((u32)(key >> 32));
                sMidx[i] = 127 - (int)(key & 0xffffffffu);
            }
        }
        __syncthreads();
        if (tid < 64) {                        // packed (gof+1)<<16 | cnt, one shfl per iter
            int NA = *pNA;
            int gof1 = -1, gof2 = -1;
            int cnt1 = 0,  cnt2 = 0;
            int ng = 0;
            #pragma unroll 8
            for (int i = 0; i < 128; ++i) {
                int   j  = sMidx[i];
                float mx = sMax[i];
                int pk = (j < 64) ? (((gof1 + 1) << 16) | cnt1)
                                  : (((gof2 + 1) << 16) | cnt2);
                pk = __shfl(pk, j & 63);
                int gj = (pk >> 16) - 1;
                int gc = pk & 0xffff;
                bool join = (mx > 0.5f) && (gj >= 0) && (gc < NA);
                int tg = join ? gj : ng;
                int ts = join ? gc : 0;
                int ncnt = join ? gc + 1 : 1;
                if (tid == 0) sA[tg * AANCH + ts] = i;
                cnt1 += (gof1 == tg);
                cnt2 += (gof2 == tg);
                if (tid == (i & 63)) {
                    if (i < 64) { gof1 = tg; cnt1 = ncnt; }
                    else        { gof2 = tg; cnt2 = ncnt; }
                }
                ng += join ? 0 : 1;
            }
        }
        __syncthreads();
        for (int t = tid; t < 384; t += 256) {
            int v = sA[t];
            aidx[t] = v;
            out_anchor[t] = (float)v;          // int32 ref chunk read back as f32 values
        }
    }
    __threadfence();
    grid.sync();

    // ================= P3: blocks 0-127 — two-pass ordered compaction + gather ===============
    if (bid < 128) {
        int g = bid;
        float* outg = out + (size_t)g * SSAMP * 5;
        int a0 = aidx[g*3+0], a1 = aidx[g*3+1], a2 = aidx[g*3+2];
        if (a0 < 0) {
            for (int t = tid; t < SSAMP * 5; t += 256) outg[t] = 0.0f;
        } else {
            bool vB = (a1 >= 0), vC = (a2 >= 0);
            const u64* rA = rowbits + (size_t)a0 * W64C;
            const u64* rB = rowbits + (size_t)(vB ? a1 : 0) * W64C;
            const u64* rC = rowbits + (size_t)(vC ? a2 : 0) * W64C;
            const u64 M21 = (1ull << 21) - 1;
            int w0 = tid * 13;                 // contiguous 13-word run per thread (3328 >= 3125)
            // ---- pass A: packed per-thread totals ----
            u64 tot = 0;
            for (int k = 0; k < 13; ++k) {
                int w = w0 + k;
                if (w < W64) {
                    u64 a = rA[w], b = vB ? rB[w] : 0ull, c = vC ? rC[w] : 0ull;
                    u64 m3 = a & b & c;
                    u64 any2 = (a & b) | (a & c) | (b & c);
                    u64 m2 = any2 & ~m3;
                    u64 m1 = (a | b | c) & ~any2;
                    tot += ((u64)__popcll(m3) << 42) | ((u64)__popcll(m2) << 21) | (u64)__popcll(m1);
                }
            }
            u64 incl = tot;
            #pragma unroll
            for (int d = 1; d < 64; d <<= 1) {
                u64 t2 = __shfl_up(incl, d);
                if (lane >= d) incl += t2;
            }
            if (lane == 63) swt[wv] = incl;
            __syncthreads();
            u64 base = incl - tot;
            for (int k = 0; k < wv; ++k) base += swt[k];
            u64 gtot = swt[0] + swt[1] + swt[2] + swt[3];
            // ---- pass B: emit at precomputed offsets ----
            u64 run = base;
            for (int k = 0; k < 13; ++k) {
                int w = w0 + k;
                if (w < W64) {
                    u64 a = rA[w], b = vB ? rB[w] : 0ull, c = vC ? rC[w] : 0ull;
                    u64 m3 = a & b & c;
                    u64 any2 = (a & b) | (a & c) | (b & c);
                    u64 m2 = any2 & ~m3;
                    u64 m1 = (a | b | c) & ~any2;
                    u32 e3 = (u32)(run >> 42);
                    u32 e2 = (u32)((run >> 21) & M21);
                    u32 e1 = (u32)(run & M21);
                    int nb = w * 64;
                    u64 mm = m3; u32 o = e3;
                    while (mm) { int b2 = __builtin_ctzll(mm); mm &= mm - 1; if (o < 256) sl3[o] = nb + b2; o++; }
                    mm = m2; o = e2;
                    while (mm) { int b2 = __builtin_ctzll(mm); mm &= mm - 1; if (o < 256) sl2[o] = nb + b2; o++; }
                    mm = m1; o = e1;
                    while (mm) { int b2 = __builtin_ctzll(mm); mm &= mm - 1; if (o < 256) sl1[o] = nb + b2; o++; }
                    run += ((u64)__popcll(m3) << 42) | ((u64)__popcll(m2) << 21) | (u64)__popcll(m1);
                }
            }
            __syncthreads();
            u32 t3 = (u32)(gtot >> 42), t2c = (u32)((gtot >> 21) & M21), t1 = (u32)(gtot & M21);
            u32 s = (u32)tid;
            int n = -1;
            if (s < t3)                  n = (int)sl3[s];
            else if (s < t3 + t2c)       n = (int)sl2[s - t3];
            else if (s < t3 + t2c + t1)  n = (int)sl1[s - t3 - t2c];
            float v0=0.f, v1=0.f, v2=0.f, v3=0.f, v4=0.f;
            if (n >= 0) {
                const float* pp = points + (size_t)n * 5;
                v0 = pp[0]; v1 = pp[1]; v2 = pp[2]; v3 = pp[3]; v4 = pp[4];
            }
            outg[s*5+0] = v0; outg[s*5+1] = v1; outg[s*5+2] = v2;
            outg[s*5+3] = v3; outg[s*5+4] = v4;
        }
    }
}

extern "C" void kernel_launch(void* const* d_in, const int* in_sizes, int n_in,
                              void* d_out, int out_size, void* d_ws, size_t ws_size,
                              hipStream_t stream)
{
    const float* points = (const float*)d_in[0];
    const float* boxes  = (const float*)d_in[1];
    const int*   labels = (const int*)d_in[2];
    const int*   pNA    = (const int*)d_in[4];
    float* out = (float*)d_out;
    char* ws = (char*)d_ws;

    size_t rowsz = (size_t)MBOX * W64C * 8;                    // 3,276,800 B
    u64*  rowbits = (u64*)ws;
    u32*  inter   = (u32*)(ws + rowsz);                        // 65,536 B (contiguous zero region)
    float* bpk    = (float*)(ws + rowsz + 65536);              // 4,096 B
    u64*  tmask   = (u64*)(ws + rowsz + 65536 + 4096);         // 4,096 B
    int*  aidx    = (int*)(ws + rowsz + 65536 + 8192);         // 1,536 B

    float* out_anchor = out + (size_t)MBOX * SSAMP * 5;        // second output chunk

    void* args[] = { (void*)&points, (void*)&boxes, (void*)&labels, (void*)&pNA,
                     (void*)&rowbits, (void*)&inter, (void*)&bpk, (void*)&tmask,
                     (void*)&aidx, (void*)&out, (void*)&out_anchor };
    hipLaunchCooperativeKernel((void*)fused, dim3(NB), dim3(BS), args, 0, stream);
}

// Round 9
// 82.176 us; speedup vs baseline: 2.7639x; 2.7639x over previous
//
#pragma clang fp contract(off)
#include <hip/hip_runtime.h>
#include <hip/hip_bf16.h>

typedef unsigned long long u64;
typedef unsigned int u32;

#define NPTS   200000
#define MBOX   128
#define W64    3125      // NPTS / 64 exactly
#define W64C   3200      // padded row stride (u64 words)
#define SSAMP  256
#define AANCH  3
#define VOXELF 0.4f
#define PCSF   -75.2f
#define TILEW  9.375f    // 150/16
#define ZU4    208896    // (128*3200*8 + 65536) / 16 bytes of zero region

// ---------------- Kernel ZP: zero rowbits+inter (all blocks) + box/tile precompute (block 0) ----
__global__ __launch_bounds__(256) void kZP(uint4* __restrict__ zbase,
                                           const float* __restrict__ boxes,
                                           float* __restrict__ bpk,
                                           u64* __restrict__ tmask)
{
    int tid = threadIdx.x;
    zbase[(size_t)blockIdx.x * 256 + tid] = make_uint4(0, 0, 0, 0);
    if (blockIdx.x != 0) return;

    __shared__ float sbx[128], sby[128], srch[128];
    if (tid < 128) {
        float bx = boxes[tid*7+0], by = boxes[tid*7+1];
        float dx = boxes[tid*7+3], dy = boxes[tid*7+4];
        float hx = dx * 0.5f, hy = dy * 0.5f;
        float sq = hx*hx;
        sq = sq + hy*hy;
        float r = sqrtf(sq);                         // radii (GAMMA=1)
        float qx = floorf((bx - PCSF) / VOXELF);
        float qy = floorf((by - PCSF) / VOXELF);
        float rv = ceilf(r / VOXELF);                // rad_vox
        bpk[tid*8+0] = bx; bpk[tid*8+1] = by; bpk[tid*8+2] = r;  bpk[tid*8+3] = qx;
        bpk[tid*8+4] = qy; bpk[tid*8+5] = rv; bpk[tid*8+6] = 0.f; bpk[tid*8+7] = 0.f;
        sbx[tid] = bx; sby[tid] = by;
        srch[tid] = VOXELF * (rv + 2.0f);            // conservative reach (>=0.8m slack)
    }
    __syncthreads();
    int tx = tid & 15, ty = tid >> 4;
    float x0 = -75.0f + tx * TILEW, x1 = x0 + TILEW;
    float y0 = -75.0f + ty * TILEW, y1 = y0 + TILEW;
    u64 m0 = 0, m1 = 0;
    for (int m = 0; m < 128; ++m) {
        float rc = srch[m];
        bool c = (sbx[m] > x0 - rc) & (sbx[m] < x1 + rc) &
                 (sby[m] > y0 - rc) & (sby[m] < y1 + rc);
        if (m < 64) m0 |= ((u64)c) << m;
        else        m1 |= ((u64)c) << (m - 64);
    }
    tmask[tid*2]   = m0;
    tmask[tid*2+1] = m1;
}

// ---------------- Kernel A: tile-pruned masks -> sparse atomicOr rowbits + atomicAdd inter --
__global__ __launch_bounds__(256) void kA(const float* __restrict__ points,
                                          const float* __restrict__ bpk,
                                          const u64* __restrict__ tmask,
                                          u64* __restrict__ rowbits,
                                          u32* __restrict__ inter)
{
    __shared__ float4 sB4[128];     // {bx,by,r,qx}
    __shared__ float2 sB2[128];     // {qy,rv}
    __shared__ u64 sTM[512];
    int tid = threadIdx.x;
    if (tid < 128) {
        const float4* bp = (const float4*)bpk;
        float4 a = bp[tid*2];
        float4 b = bp[tid*2+1];
        sB4[tid] = a;
        sB2[tid] = make_float2(b.x, b.y);
    }
    sTM[tid]       = tmask[tid];
    sTM[tid + 256] = tmask[tid + 256];
    __syncthreads();

    int n = blockIdx.x * 256 + tid;
    if (n >= NPTS) return;
    float px = points[n*5+0], py = points[n*5+1];
    float cxn = floorf((px - PCSF) / VOXELF);
    float cyn = floorf((py - PCSF) / VOXELF);
    int tx = (int)floorf((px + 75.0f) * (1.0f / TILEW));
    int ty = (int)floorf((py + 75.0f) * (1.0f / TILEW));
    tx = tx < 0 ? 0 : (tx > 15 ? 15 : tx);
    ty = ty < 0 ? 0 : (ty > 15 ? 15 : ty);
    int tile = ty * 16 + tx;
    u64 c0 = sTM[tile*2], c1 = sTM[tile*2+1];
    u64 h0 = 0, h1 = 0;
    bool voxany = false;
    while (c0) {
        int m = __builtin_ctzll(c0); c0 &= c0 - 1;
        float4 bd = sB4[m]; float2 be = sB2[m];
        float ddx = px - bd.x, ddy = py - bd.y;
        float sq = ddx*ddx;
        sq = sq + ddy*ddy;
        float dis = sqrtf(sq);
        bool hit = (dis <= bd.z);
        bool vox = (fabsf(bd.w - cxn) < be.y) & (fabsf(be.x - cyn) < be.y);
        voxany |= vox;
        h0 |= ((u64)hit) << m;
    }
    while (c1) {
        int m = __builtin_ctzll(c1); c1 &= c1 - 1;
        float4 bd = sB4[m + 64]; float2 be = sB2[m + 64];
        float ddx = px - bd.x, ddy = py - bd.y;
        float sq = ddx*ddx;
        sq = sq + ddy*ddy;
        float dis = sqrtf(sq);
        bool hit = (dis <= bd.z);
        bool vox = (fabsf(bd.w - cxn) < be.y) & (fabsf(be.x - cyn) < be.y);
        voxany |= vox;
        h1 |= ((u64)hit) << m;
    }
    if (!voxany) { h0 = 0; h1 = 0; }       // point_mask = circle & vmask
    if ((h0 | h1) == 0) return;

    int w = n >> 6, lane = n & 63;
    u64 lanebit = 1ull << lane;
    u64 e = h0;
    while (e) {
        int m = __builtin_ctzll(e); e &= e - 1;
        atomicOr(&rowbits[(size_t)m * W64C + w], lanebit);
        u64 f = h0;
        while (f) { int j = __builtin_ctzll(f); f &= f - 1; atomicAdd(&inter[m*128 + j], 1u); }
        f = h1;
        while (f) { int j = __builtin_ctzll(f); f &= f - 1; atomicAdd(&inter[m*128 + 64 + j], 1u); }
    }
    e = h1;
    while (e) {
        int m = __builtin_ctzll(e); e &= e - 1;
        atomicOr(&rowbits[(size_t)(m + 64) * W64C + w], lanebit);
        u64 f = h0;
        while (f) { int j = __builtin_ctzll(f); f &= f - 1; atomicAdd(&inter[(m+64)*128 + j], 1u); }
        f = h1;
        while (f) { int j = __builtin_ctzll(f); f &= f - 1; atomicAdd(&inter[(m+64)*128 + 64 + j], 1u); }
    }
}

// ---------------- Kernel CD: per-block {argmax + packed greedy} (redundant) + own-group gather ---
__global__ __launch_bounds__(256) void kCD(const u32* __restrict__ inter,
                                           const int* __restrict__ labels,
                                           const int* __restrict__ pNA,
                                           const u64* __restrict__ rowbits,
                                           const float* __restrict__ points,
                                           float* __restrict__ out,
                                           float* __restrict__ out_anchor)
{
    __shared__ u32   scnt[128];
    __shared__ int   slab[128];
    __shared__ float sMax[128];
    __shared__ int   sMidx[128];
    __shared__ int   sA[384];
    __shared__ u32   sl3[256], sl2[256], sl1[256];
    __shared__ u64   swt[4];
    int tid = threadIdx.x, bid = blockIdx.x;
    int lane = tid & 63, wv = tid >> 6;

    if (tid < 128) {
        scnt[tid] = inter[tid * 128 + tid];
        slab[tid] = labels[tid];
        sA[tid] = -1; sA[tid + 128] = -1; sA[tid + 256] = -1;
    }
    __syncthreads();
    // ---- argmax: 4 waves x 32 rows ----
    for (int t = 0; t < 32; ++t) {
        int i = wv * 32 + t;
        u32 ci = scnt[i];
        int li = slab[i];
        u32 I1 = inter[i * 128 + lane];
        u32 I2 = inter[i * 128 + 64 + lane];
        int j1 = lane, j2 = lane + 64;
        long un1 = (long)ci + (long)scnt[j1] - (long)I1;
        long un2 = (long)ci + (long)scnt[j2] - (long)I2;
        float v1 = 0.0f, v2 = 0.0f;
        if ((j1 != i) && (slab[j1] == li) && (un1 > 0))
            v1 = (float)I1 / fmaxf((float)un1, 1.0f);
        if ((j2 != i) && (slab[j2] == li) && (un2 > 0))
            v2 = (float)I2 / fmaxf((float)un2, 1.0f);
        u64 k1 = ((u64)__float_as_uint(v1) << 32) | (u32)(127 - j1);
        u64 k2 = ((u64)__float_as_uint(v2) << 32) | (u32)(127 - j2);
        u64 key = (k1 > k2) ? k1 : k2;
        #pragma unroll
        for (int d = 1; d < 64; d <<= 1) {
            u64 o = __shfl_xor(key, d);
            key = (key > o) ? key : o;
        }
        if (lane == 0) {
            sMax[i]  = __uint_as_float((u32)(key >> 32));
            sMidx[i] = 127 - (int)(key & 0xffffffffu);
        }
    }
    __syncthreads();
    // ---- packed greedy scan on wave 0: (gof+1)<<16 | cnt, one shfl per iter ----
    if (tid < 64) {
        int NA = *pNA;
        int gof1 = -1, gof2 = -1;
        int cnt1 = 0,  cnt2 = 0;
        int ng = 0;
        #pragma unroll 8
        for (int i = 0; i < 128; ++i) {
            int   j  = sMidx[i];
            float mx = sMax[i];
            int pk = (j < 64) ? (((gof1 + 1) << 16) | cnt1)
                              : (((gof2 + 1) << 16) | cnt2);
            pk = __shfl(pk, j & 63);
            int gj = (pk >> 16) - 1;
            int gc = pk & 0xffff;
            bool join = (mx > 0.5f) && (gj >= 0) && (gc < NA);
            int tg = join ? gj : ng;
            int ts = join ? gc : 0;
            int ncnt = join ? gc + 1 : 1;
            if (tid == 0) sA[tg * AANCH + ts] = i;
            cnt1 += (gof1 == tg);
            cnt2 += (gof2 == tg);
            if (tid == (i & 63)) {
                if (i < 64) { gof1 = tg; cnt1 = ncnt; }
                else        { gof2 = tg; cnt2 = ncnt; }
            }
            ng += join ? 0 : 1;
        }
    }
    __syncthreads();
    if (bid == 0) {
        for (int t = tid; t < 384; t += 256)
            out_anchor[t] = (float)sA[t];   // int32 ref chunk read back as f32 values
    }
    // ---- own-group two-pass ordered compaction + gather ----
    int g = bid;
    float* outg = out + (size_t)g * SSAMP * 5;
    int a0 = sA[g*3+0], a1 = sA[g*3+1], a2 = sA[g*3+2];
    if (a0 < 0) {
        for (int t = tid; t < SSAMP * 5; t += 256) outg[t] = 0.0f;
        return;
    }
    bool vB = (a1 >= 0), vC = (a2 >= 0);
    const u64* rA = rowbits + (size_t)a0 * W64C;
    const u64* rB = rowbits + (size_t)(vB ? a1 : 0) * W64C;
    const u64* rC = rowbits + (size_t)(vC ? a2 : 0) * W64C;
    const u64 M21 = (1ull << 21) - 1;
    int w0 = tid * 13;                 // contiguous 13-word run per thread (3328 >= 3125)
    u64 tot = 0;
    for (int k = 0; k < 13; ++k) {
        int w = w0 + k;
        if (w < W64) {
            u64 a = rA[w], b = vB ? rB[w] : 0ull, c = vC ? rC[w] : 0ull;
            u64 m3 = a & b & c;
            u64 any2 = (a & b) | (a & c) | (b & c);
            u64 m2 = any2 & ~m3;
            u64 m1 = (a | b | c) & ~any2;
            tot += ((u64)__popcll(m3) << 42) | ((u64)__popcll(m2) << 21) | (u64)__popcll(m1);
        }
    }
    u64 incl = tot;
    #pragma unroll
    for (int d = 1; d < 64; d <<= 1) {
        u64 t2 = __shfl_up(incl, d);
        if (lane >= d) incl += t2;
    }
    if (lane == 63) swt[wv] = incl;
    __syncthreads();
    u64 base = incl - tot;
    for (int k = 0; k < wv; ++k) base += swt[k];
    u64 gtot = swt[0] + swt[1] + swt[2] + swt[3];
    u64 run = base;
    for (int k = 0; k < 13; ++k) {
        int w = w0 + k;
        if (w < W64) {
            u64 a = rA[w], b = vB ? rB[w] : 0ull, c = vC ? rC[w] : 0ull;
            u64 m3 = a & b & c;
            u64 any2 = (a & b) | (a & c) | (b & c);
            u64 m2 = any2 & ~m3;
            u64 m1 = (a | b | c) & ~any2;
            u32 e3 = (u32)(run >> 42);
            u32 e2 = (u32)((run >> 21) & M21);
            u32 e1 = (u32)(run & M21);
            int nb = w * 64;
            u64 mm = m3; u32 o = e3;
            while (mm) { int b2 = __builtin_ctzll(mm); mm &= mm - 1; if (o < 256) sl3[o] = nb + b2; o++; }
            mm = m2; o = e2;
            while (mm) { int b2 = __builtin_ctzll(mm); mm &= mm - 1; if (o < 256) sl2[o] = nb + b2; o++; }
            mm = m1; o = e1;
            while (mm) { int b2 = __builtin_ctzll(mm); mm &= mm - 1; if (o < 256) sl1[o] = nb + b2; o++; }
            run += ((u64)__popcll(m3) << 42) | ((u64)__popcll(m2) << 21) | (u64)__popcll(m1);
        }
    }
    __syncthreads();
    u32 t3 = (u32)(gtot >> 42), t2c = (u32)((gtot >> 21) & M21), t1 = (u32)(gtot & M21);
    u32 s = (u32)tid;
    int n = -1;
    if (s < t3)                  n = (int)sl3[s];
    else if (s < t3 + t2c)       n = (int)sl2[s - t3];
    else if (s < t3 + t2c + t1)  n = (int)sl1[s - t3 - t2c];
    float v0=0.f, v1=0.f, v2=0.f, v3=0.f, v4=0.f;
    if (n >= 0) {
        const float* pp = points + (size_t)n * 5;
        v0 = pp[0]; v1 = pp[1]; v2 = pp[2]; v3 = pp[3]; v4 = pp[4];
    }
    outg[s*5+0] = v0; outg[s*5+1] = v1; outg[s*5+2] = v2;
    outg[s*5+3] = v3; outg[s*5+4] = v4;
}

extern "C" void kernel_launch(void* const* d_in, const int* in_sizes, int n_in,
                              void* d_out, int out_size, void* d_ws, size_t ws_size,
                              hipStream_t stream)
{
    const float* points = (const float*)d_in[0];
    const float* boxes  = (const float*)d_in[1];
    const int*   labels = (const int*)d_in[2];
    const int*   pNA    = (const int*)d_in[4];
    float* out = (float*)d_out;
    char* ws = (char*)d_ws;

    size_t rowsz = (size_t)MBOX * W64C * 8;                    // 3,276,800 B
    u64*  rowbits = (u64*)ws;
    u32*  inter   = (u32*)(ws + rowsz);                        // 65,536 B (contiguous zero region)
    float* bpk    = (float*)(ws + rowsz + 65536);              // 4,096 B
    u64*  tmask   = (u64*)(ws + rowsz + 65536 + 4096);         // 4,096 B

    float* out_anchor = out + (size_t)MBOX * SSAMP * 5;        // second output chunk

    kZP<<<816, 256, 0, stream>>>((uint4*)ws, boxes, bpk, tmask);
    kA<<<(NPTS + 255) / 256, 256, 0, stream>>>(points, bpk, tmask, rowbits, inter);
    kCD<<<MBOX, 256, 0, stream>>>(inter, labels, pNA, rowbits, points, out, out_anchor);
}

// Round 10
// 68.560 us; speedup vs baseline: 3.3128x; 1.1986x over previous
//
#pragma clang fp contract(off)
#include <hip/hip_runtime.h>
#include <hip/hip_bf16.h>

typedef unsigned long long u64;
typedef unsigned int u32;

#define NPTS   200000
#define MBOX   128
#define W64    3125      // NPTS / 64 exactly
#define W64C   3200      // padded row stride (u64 words)
#define SSAMP  256
#define AANCH  3
#define VOXELF 0.4f
#define PCSF   -75.2f
#define TILEW  9.375f    // 150/16

// ---------------- Kernel ZP: zero rowbits+inter (all blocks) + box/tile precompute (block 0) ----
__global__ __launch_bounds__(256) void kZP(uint4* __restrict__ zbase,
                                           const float* __restrict__ boxes,
                                           float* __restrict__ bpk,
                                           u64* __restrict__ tmask)
{
    int tid = threadIdx.x;
    zbase[(size_t)blockIdx.x * 256 + tid] = make_uint4(0, 0, 0, 0);
    if (blockIdx.x != 0) return;

    __shared__ float sbx[128], sby[128], srch[128];
    if (tid < 128) {
        float bx = boxes[tid*7+0], by = boxes[tid*7+1];
        float dx = boxes[tid*7+3], dy = boxes[tid*7+4];
        float hx = dx * 0.5f, hy = dy * 0.5f;
        float sq = hx*hx;
        sq = sq + hy*hy;
        float r = sqrtf(sq);                         // radii (GAMMA=1)
        float qx = floorf((bx - PCSF) / VOXELF);
        float qy = floorf((by - PCSF) / VOXELF);
        float rv = ceilf(r / VOXELF);                // rad_vox
        bpk[tid*8+0] = bx; bpk[tid*8+1] = by; bpk[tid*8+2] = r;  bpk[tid*8+3] = qx;
        bpk[tid*8+4] = qy; bpk[tid*8+5] = rv; bpk[tid*8+6] = 0.f; bpk[tid*8+7] = 0.f;
        sbx[tid] = bx; sby[tid] = by;
        srch[tid] = VOXELF * (rv + 2.0f);            // conservative reach (>=0.8m slack)
    }
    __syncthreads();
    int tx = tid & 15, ty = tid >> 4;
    float x0 = -75.0f + tx * TILEW, x1 = x0 + TILEW;
    float y0 = -75.0f + ty * TILEW, y1 = y0 + TILEW;
    u64 m0 = 0, m1 = 0;
    for (int m = 0; m < 128; ++m) {
        float rc = srch[m];
        bool c = (sbx[m] > x0 - rc) & (sbx[m] < x1 + rc) &
                 (sby[m] > y0 - rc) & (sby[m] < y1 + rc);
        if (m < 64) m0 |= ((u64)c) << m;
        else        m1 |= ((u64)c) << (m - 64);
    }
    tmask[tid*2]   = m0;
    tmask[tid*2+1] = m1;
}

// ---------------- Kernel A: tile-pruned masks -> sparse atomicOr rowbits + atomicAdd inter --
__global__ __launch_bounds__(256) void kA(const float* __restrict__ points,
                                          const float* __restrict__ bpk,
                                          const u64* __restrict__ tmask,
                                          u64* __restrict__ rowbits,
                                          u32* __restrict__ inter)
{
    __shared__ float4 sB4[128];     // {bx,by,r,qx}
    __shared__ float2 sB2[128];     // {qy,rv}
    __shared__ u64 sTM[512];
    int tid = threadIdx.x;
    if (tid < 128) {
        const float4* bp = (const float4*)bpk;
        float4 a = bp[tid*2];
        float4 b = bp[tid*2+1];
        sB4[tid] = a;
        sB2[tid] = make_float2(b.x, b.y);
    }
    sTM[tid]       = tmask[tid];
    sTM[tid + 256] = tmask[tid + 256];
    __syncthreads();

    int n = blockIdx.x * 256 + tid;
    if (n >= NPTS) return;
    float px = points[n*5+0], py = points[n*5+1];
    float cxn = floorf((px - PCSF) / VOXELF);
    float cyn = floorf((py - PCSF) / VOXELF);
    int tx = (int)floorf((px + 75.0f) * (1.0f / TILEW));
    int ty = (int)floorf((py + 75.0f) * (1.0f / TILEW));
    tx = tx < 0 ? 0 : (tx > 15 ? 15 : tx);
    ty = ty < 0 ? 0 : (ty > 15 ? 15 : ty);
    int tile = ty * 16 + tx;
    u64 c0 = sTM[tile*2], c1 = sTM[tile*2+1];
    u64 h0 = 0, h1 = 0;
    bool voxany = false;
    while (c0) {
        int m = __builtin_ctzll(c0); c0 &= c0 - 1;
        float4 bd = sB4[m]; float2 be = sB2[m];
        float ddx = px - bd.x, ddy = py - bd.y;
        float sq = ddx*ddx;
        sq = sq + ddy*ddy;
        float dis = sqrtf(sq);
        bool hit = (dis <= bd.z);
        bool vox = (fabsf(bd.w - cxn) < be.y) & (fabsf(be.x - cyn) < be.y);
        voxany |= vox;
        h0 |= ((u64)hit) << m;
    }
    while (c1) {
        int m = __builtin_ctzll(c1); c1 &= c1 - 1;
        float4 bd = sB4[m + 64]; float2 be = sB2[m + 64];
        float ddx = px - bd.x, ddy = py - bd.y;
        float sq = ddx*ddx;
        sq = sq + ddy*ddy;
        float dis = sqrtf(sq);
        bool hit = (dis <= bd.z);
        bool vox = (fabsf(bd.w - cxn) < be.y) & (fabsf(be.x - cyn) < be.y);
        voxany |= vox;
        h1 |= ((u64)hit) << m;
    }
    if (!voxany) { h0 = 0; h1 = 0; }       // point_mask = circle & vmask
    if ((h0 | h1) == 0) return;

    int w = n >> 6, lane = n & 63;
    u64 lanebit = 1ull << lane;
    u64 e = h0;
    while (e) {
        int m = __builtin_ctzll(e); e &= e - 1;
        atomicOr(&rowbits[(size_t)m * W64C + w], lanebit);
        u64 f = h0;
        while (f) { int j = __builtin_ctzll(f); f &= f - 1; atomicAdd(&inter[m*128 + j], 1u); }
        f = h1;
        while (f) { int j = __builtin_ctzll(f); f &= f - 1; atomicAdd(&inter[m*128 + 64 + j], 1u); }
    }
    e = h1;
    while (e) {
        int m = __builtin_ctzll(e); e &= e - 1;
        atomicOr(&rowbits[(size_t)(m + 64) * W64C + w], lanebit);
        u64 f = h0;
        while (f) { int j = __builtin_ctzll(f); f &= f - 1; atomicAdd(&inter[(m+64)*128 + j], 1u); }
        f = h1;
        while (f) { int j = __builtin_ctzll(f); f &= f - 1; atomicAdd(&inter[(m+64)*128 + 64 + j], 1u); }
    }
}

// ---------------- Kernel C1: per-row argmax — f32 butterfly + ballot tie-break ----------------
__global__ __launch_bounds__(64) void kC1(const u32* __restrict__ inter,
                                          const int* __restrict__ labels,
                                          float* __restrict__ mmaxW,
                                          int* __restrict__ midxW)
{
    int i = blockIdx.x, lane = threadIdx.x;
    int j1 = lane, j2 = lane + 64;
    u32 ci = inter[i * 128 + i];                 // uniform
    int li = labels[i];
    u32 I1 = inter[i * 128 + j1];                // coalesced
    u32 I2 = inter[i * 128 + j2];
    u32 c1 = inter[j1 * 128 + j1];               // strided diag, L2-hot
    u32 c2 = inter[j2 * 128 + j2];
    int l1 = labels[j1], l2 = labels[j2];
    long un1 = (long)ci + (long)c1 - (long)I1;
    long un2 = (long)ci + (long)c2 - (long)I2;
    float v1 = 0.0f, v2 = 0.0f;
    if ((j1 != i) && (l1 == li) && (un1 > 0))
        v1 = (float)I1 / fmaxf((float)un1, 1.0f);
    if ((j2 != i) && (l2 == li) && (un2 > 0))
        v2 = (float)I2 / fmaxf((float)un2, 1.0f);
    float vm = fmaxf(v1, v2);
    #pragma unroll
    for (int d = 1; d < 64; d <<= 1)
        vm = fmaxf(vm, __shfl_xor(vm, d));
    u64 b1 = __ballot(v1 == vm);
    u64 b2 = __ballot(v2 == vm);
    int j = b1 ? __builtin_ctzll(b1) : 64 + __builtin_ctzll(b2);   // first-index argmax
    if (lane == 0) { mmaxW[i] = vm; midxW[i] = j; }
}

// ---------------- Kernel C2: single-wave greedy grouping; packed state, one shfl per iter ------
__global__ __launch_bounds__(64) void kC2(const float* __restrict__ mmaxW,
                                          const int* __restrict__ midxW,
                                          const int* __restrict__ pNA,
                                          int* __restrict__ aidx_ws,
                                          float* __restrict__ out_anchor)
{
    __shared__ int sA[128 * AANCH];
    int lane = threadIdx.x;
    int NA = *pNA;
    for (int t = lane; t < 128 * AANCH; t += 64) sA[t] = -1;
    int   mia = midxW[lane], mib = midxW[lane + 64];
    float mxa = mmaxW[lane], mxb = mmaxW[lane + 64];
    int gof1 = -1, gof2 = -1;
    int cnt1 = 0,  cnt2 = 0;
    int ng = 0;
    #pragma unroll 8
    for (int i = 0; i < 128; ++i) {
        int   j  = __shfl((i < 64) ? mia : mib, i & 63);   // static per-i, hoistable
        float mx = __shfl((i < 64) ? mxa : mxb, i & 63);
        int pk = (j < 64) ? (((gof1 + 1) << 16) | cnt1)
                          : (((gof2 + 1) << 16) | cnt2);
        pk = __shfl(pk, j & 63);           // the ONLY chained cross-lane op
        int gj = (pk >> 16) - 1;
        int gc = pk & 0xffff;
        bool join = (mx > 0.5f) && (gj >= 0) && (gc < NA);
        int tg = join ? gj : ng;
        int ts = join ? gc : 0;
        int ncnt = join ? gc + 1 : 1;
        if (lane == 0) sA[tg * AANCH + ts] = i;
        cnt1 += (gof1 == tg);
        cnt2 += (gof2 == tg);
        if (lane == (i & 63)) {
            if (i < 64) { gof1 = tg; cnt1 = ncnt; }
            else        { gof2 = tg; cnt2 = ncnt; }
        }
        ng += join ? 0 : 1;
    }
    __syncthreads();
    for (int t = lane; t < 128 * AANCH; t += 64) {
        int v = sA[t];
        aidx_ws[t] = v;
        out_anchor[t] = (float)v;          // int32 ref chunk read back as f32 values
    }
}

// ---------------- Kernel D: merged masks, coalesced chunked ordered compaction + gather --------
__global__ __launch_bounds__(256) void kD(const u64* __restrict__ rowbits,
                                          const int* __restrict__ aidx_ws,
                                          const float* __restrict__ points,
                                          float* __restrict__ out)
{
    int g = blockIdx.x, tid = threadIdx.x;
    __shared__ u32 sl3[256], sl2[256], sl1[256];
    __shared__ u64 wtot[4];
    __shared__ u64 carried;
    float* outg = out + (size_t)g * SSAMP * 5;
    int a0 = aidx_ws[g*3+0], a1 = aidx_ws[g*3+1], a2 = aidx_ws[g*3+2];
    if (a0 < 0) {                      // invalid group -> all zeros
        for (int t = tid; t < SSAMP * 5; t += 256) outg[t] = 0.0f;
        return;
    }
    bool vB = (a1 >= 0), vC = (a2 >= 0);
    const u64* rA = rowbits + (size_t)a0 * W64C;
    const u64* rB = rowbits + (size_t)(vB ? a1 : 0) * W64C;
    const u64* rC = rowbits + (size_t)(vC ? a2 : 0) * W64C;
    if (tid == 0) carried = 0;
    __syncthreads();
    int lane = tid & 63, wv = tid >> 6;
    const u64 M21 = (1ull << 21) - 1;
    for (int ch = 0; ch < 13; ++ch) {
        int w = ch * 256 + tid;        // coalesced
        bool inr = (w < W64);
        u64 a = 0, b = 0, c = 0;
        if (inr) {
            a = rA[w];
            b = vB ? rB[w] : 0ull;
            c = vC ? rC[w] : 0ull;
        }
        u64 m3 = a & b & c;
        u64 any2 = (a & b) | (a & c) | (b & c);
        u64 m2 = any2 & ~m3;
        u64 m1 = (a | b | c) & ~any2;
        u64 p = ((u64)__popcll(m3) << 42) | ((u64)__popcll(m2) << 21) | (u64)__popcll(m1);
        u64 own = p;
        for (int d = 1; d < 64; d <<= 1) {       // inclusive wave scan (packed fields)
            u64 t = __shfl_up(p, d);
            if (lane >= d) p += t;
        }
        if (lane == 63) wtot[wv] = p;
        u64 excl = p - own;
        __syncthreads();
        u64 off = carried + excl;
        for (int k = 0; k < wv; ++k) off += wtot[k];
        u32 e3 = (u32)(off >> 42);
        u32 e2 = (u32)((off >> 21) & M21);
        u32 e1 = (u32)(off & M21);
        int nb = w * 64;
        u64 mm = m3; u32 o = e3;
        while (mm) { int b2 = __builtin_ctzll(mm); mm &= mm - 1; if (o < 256) sl3[o] = nb + b2; o++; }
        mm = m2; o = e2;
        while (mm) { int b2 = __builtin_ctzll(mm); mm &= mm - 1; if (o < 256) sl2[o] = nb + b2; o++; }
        mm = m1; o = e1;
        while (mm) { int b2 = __builtin_ctzll(mm); mm &= mm - 1; if (o < 256) sl1[o] = nb + b2; o++; }
        __syncthreads();
        if (tid == 0) carried += wtot[0] + wtot[1] + wtot[2] + wtot[3];
        __syncthreads();
    }
    u64 car = carried;
    u32 t3 = (u32)(car >> 42), t2 = (u32)((car >> 21) & M21), t1 = (u32)(car & M21);
    u32 s = (u32)tid;
    int n = -1;
    if (s < t3)                 n = (int)sl3[s];
    else if (s < t3 + t2)       n = (int)sl2[s - t3];
    else if (s < t3 + t2 + t1)  n = (int)sl1[s - t3 - t2];
    float v0=0.f, v1=0.f, v2=0.f, v3=0.f, v4=0.f;
    if (n >= 0) {
        const float* pp = points + (size_t)n * 5;
        v0 = pp[0]; v1 = pp[1]; v2 = pp[2]; v3 = pp[3]; v4 = pp[4];
    }
    outg[s*5+0] = v0; outg[s*5+1] = v1; outg[s*5+2] = v2;
    outg[s*5+3] = v3; outg[s*5+4] = v4;
}

extern "C" void kernel_launch(void* const* d_in, const int* in_sizes, int n_in,
                              void* d_out, int out_size, void* d_ws, size_t ws_size,
                              hipStream_t stream)
{
    const float* points = (const float*)d_in[0];
    const float* boxes  = (const float*)d_in[1];
    const int*   labels = (const int*)d_in[2];
    const int*   pNA    = (const int*)d_in[4];
    float* out = (float*)d_out;
    char* ws = (char*)d_ws;

    size_t rowsz = (size_t)MBOX * W64C * 8;                    // 3,276,800 B
    u64*  rowbits = (u64*)ws;
    u32*  inter   = (u32*)(ws + rowsz);                        // 65,536 B (contiguous zero region)
    float* bpk    = (float*)(ws + rowsz + 65536);              // 4,096 B
    u64*  tmask   = (u64*)(ws + rowsz + 65536 + 4096);         // 4,096 B
    float* mmaxW  = (float*)(ws + rowsz + 65536 + 8192);       // 512 B
    int*   midxW  = (int*)(ws + rowsz + 65536 + 8704);         // 512 B
    int*   aidx   = (int*)(ws + rowsz + 65536 + 9216);         // 1,536 B

    float* out_anchor = out + (size_t)MBOX * SSAMP * 5;        // second output chunk

    kZP<<<816, 256, 0, stream>>>((uint4*)ws, boxes, bpk, tmask);
    kA<<<(NPTS + 255) / 256, 256, 0, stream>>>(points, bpk, tmask, rowbits, inter);
    kC1<<<MBOX, 64, 0, stream>>>(inter, labels, mmaxW, midxW);
    kC2<<<1, 64, 0, stream>>>(mmaxW, midxW, pNA, aidx, out_anchor);
    kD<<<MBOX, 256, 0, stream>>>(rowbits, aidx, points, out);
}

// Round 11
// 62.147 us; speedup vs baseline: 3.6547x; 1.1032x over previous
//
#pragma clang fp contract(off)
#include <hip/hip_runtime.h>
#include <hip/hip_bf16.h>

typedef unsigned long long u64;
typedef unsigned int u32;

#define NPTS   200000
#define MBOX   128
#define W64    3125      // NPTS / 64 exactly
#define W64C   3200      // padded row stride (u64 words)
#define SSAMP  256
#define AANCH  3
#define VOXELF 0.4f
#define PCSF   -75.2f
#define TILEW  9.375f    // 150/16

// ---------------- Kernel ZP: zero rowbits+inter (all blocks) + box/tile precompute (block 0) ----
__global__ __launch_bounds__(256) void kZP(uint4* __restrict__ zbase,
                                           const float* __restrict__ boxes,
                                           float* __restrict__ bpk,
                                           u64* __restrict__ tmask)
{
    int tid = threadIdx.x;
    zbase[(size_t)blockIdx.x * 256 + tid] = make_uint4(0, 0, 0, 0);
    if (blockIdx.x != 0) return;

    __shared__ float sbx[128], sby[128], srch[128];
    if (tid < 128) {
        float bx = boxes[tid*7+0], by = boxes[tid*7+1];
        float dx = boxes[tid*7+3], dy = boxes[tid*7+4];
        float hx = dx * 0.5f, hy = dy * 0.5f;
        float sq = hx*hx;
        sq = sq + hy*hy;
        float r = sqrtf(sq);                         // radii (GAMMA=1)
        float qx = floorf((bx - PCSF) / VOXELF);
        float qy = floorf((by - PCSF) / VOXELF);
        float rv = ceilf(r / VOXELF);                // rad_vox
        bpk[tid*8+0] = bx; bpk[tid*8+1] = by; bpk[tid*8+2] = r;  bpk[tid*8+3] = qx;
        bpk[tid*8+4] = qy; bpk[tid*8+5] = rv; bpk[tid*8+6] = 0.f; bpk[tid*8+7] = 0.f;
        sbx[tid] = bx; sby[tid] = by;
        srch[tid] = VOXELF * (rv + 2.0f);            // conservative reach (>=0.8m slack)
    }
    __syncthreads();
    int tx = tid & 15, ty = tid >> 4;
    float x0 = -75.0f + tx * TILEW, x1 = x0 + TILEW;
    float y0 = -75.0f + ty * TILEW, y1 = y0 + TILEW;
    u64 m0 = 0, m1 = 0;
    for (int m = 0; m < 128; ++m) {
        float rc = srch[m];
        bool c = (sbx[m] > x0 - rc) & (sbx[m] < x1 + rc) &
                 (sby[m] > y0 - rc) & (sby[m] < y1 + rc);
        if (m < 64) m0 |= ((u64)c) << m;
        else        m1 |= ((u64)c) << (m - 64);
    }
    tmask[tid*2]   = m0;
    tmask[tid*2+1] = m1;
}

// ---------------- Kernel A: tile-pruned masks -> sparse atomicOr rowbits + atomicAdd inter --
__global__ __launch_bounds__(256) void kA(const float* __restrict__ points,
                                          const float* __restrict__ bpk,
                                          const u64* __restrict__ tmask,
                                          u64* __restrict__ rowbits,
                                          u32* __restrict__ inter)
{
    __shared__ float4 sB4[128];     // {bx,by,r,qx}
    __shared__ float2 sB2[128];     // {qy,rv}
    __shared__ u64 sTM[512];
    int tid = threadIdx.x;
    if (tid < 128) {
        const float4* bp = (const float4*)bpk;
        float4 a = bp[tid*2];
        float4 b = bp[tid*2+1];
        sB4[tid] = a;
        sB2[tid] = make_float2(b.x, b.y);
    }
    sTM[tid]       = tmask[tid];
    sTM[tid + 256] = tmask[tid + 256];
    __syncthreads();

    int n = blockIdx.x * 256 + tid;
    if (n >= NPTS) return;
    float px = points[n*5+0], py = points[n*5+1];
    float cxn = floorf((px - PCSF) / VOXELF);
    float cyn = floorf((py - PCSF) / VOXELF);
    int tx = (int)floorf((px + 75.0f) * (1.0f / TILEW));
    int ty = (int)floorf((py + 75.0f) * (1.0f / TILEW));
    tx = tx < 0 ? 0 : (tx > 15 ? 15 : tx);
    ty = ty < 0 ? 0 : (ty > 15 ? 15 : ty);
    int tile = ty * 16 + tx;
    u64 c0 = sTM[tile*2], c1 = sTM[tile*2+1];
    u64 h0 = 0, h1 = 0;
    bool voxany = false;
    while (c0) {
        int m = __builtin_ctzll(c0); c0 &= c0 - 1;
        float4 bd = sB4[m]; float2 be = sB2[m];
        float ddx = px - bd.x, ddy = py - bd.y;
        float sq = ddx*ddx;
        sq = sq + ddy*ddy;
        float dis = sqrtf(sq);
        bool hit = (dis <= bd.z);
        bool vox = (fabsf(bd.w - cxn) < be.y) & (fabsf(be.x - cyn) < be.y);
        voxany |= vox;
        h0 |= ((u64)hit) << m;
    }
    while (c1) {
        int m = __builtin_ctzll(c1); c1 &= c1 - 1;
        float4 bd = sB4[m + 64]; float2 be = sB2[m + 64];
        float ddx = px - bd.x, ddy = py - bd.y;
        float sq = ddx*ddx;
        sq = sq + ddy*ddy;
        float dis = sqrtf(sq);
        bool hit = (dis <= bd.z);
        bool vox = (fabsf(bd.w - cxn) < be.y) & (fabsf(be.x - cyn) < be.y);
        voxany |= vox;
        h1 |= ((u64)hit) << m;
    }
    if (!voxany) { h0 = 0; h1 = 0; }       // point_mask = circle & vmask
    if ((h0 | h1) == 0) return;

    int w = n >> 6, lane = n & 63;
    u64 lanebit = 1ull << lane;
    u64 e = h0;
    while (e) {
        int m = __builtin_ctzll(e); e &= e - 1;
        atomicOr(&rowbits[(size_t)m * W64C + w], lanebit);
        u64 f = h0;
        while (f) { int j = __builtin_ctzll(f); f &= f - 1; atomicAdd(&inter[m*128 + j], 1u); }
        f = h1;
        while (f) { int j = __builtin_ctzll(f); f &= f - 1; atomicAdd(&inter[m*128 + 64 + j], 1u); }
    }
    e = h1;
    while (e) {
        int m = __builtin_ctzll(e); e &= e - 1;
        atomicOr(&rowbits[(size_t)(m + 64) * W64C + w], lanebit);
        u64 f = h0;
        while (f) { int j = __builtin_ctzll(f); f &= f - 1; atomicAdd(&inter[(m+64)*128 + j], 1u); }
        f = h1;
        while (f) { int j = __builtin_ctzll(f); f &= f - 1; atomicAdd(&inter[(m+64)*128 + 64 + j], 1u); }
    }
}

// ---------------- Kernel C1: per-row argmax — f32 butterfly + ballot tie-break ----------------
__global__ __launch_bounds__(64) void kC1(const u32* __restrict__ inter,
                                          const int* __restrict__ labels,
                                          float* __restrict__ mmaxW,
                                          int* __restrict__ midxW)
{
    int i = blockIdx.x, lane = threadIdx.x;
    int j1 = lane, j2 = lane + 64;
    u32 ci = inter[i * 128 + i];                 // uniform
    int li = labels[i];
    u32 I1 = inter[i * 128 + j1];                // coalesced
    u32 I2 = inter[i * 128 + j2];
    u32 c1 = inter[j1 * 128 + j1];               // strided diag, L2-hot
    u32 c2 = inter[j2 * 128 + j2];
    int l1 = labels[j1], l2 = labels[j2];
    long un1 = (long)ci + (long)c1 - (long)I1;
    long un2 = (long)ci + (long)c2 - (long)I2;
    float v1 = 0.0f, v2 = 0.0f;
    if ((j1 != i) && (l1 == li) && (un1 > 0))
        v1 = (float)I1 / fmaxf((float)un1, 1.0f);
    if ((j2 != i) && (l2 == li) && (un2 > 0))
        v2 = (float)I2 / fmaxf((float)un2, 1.0f);
    float vm = fmaxf(v1, v2);
    #pragma unroll
    for (int d = 1; d < 64; d <<= 1)
        vm = fmaxf(vm, __shfl_xor(vm, d));
    u64 b1 = __ballot(v1 == vm);
    u64 b2 = __ballot(v2 == vm);
    int j = b1 ? __builtin_ctzll(b1) : 64 + __builtin_ctzll(b2);   // first-index argmax
    if (lane == 0) { mmaxW[i] = vm; midxW[i] = j; }
}

// ---------------- Kernel D: per-block greedy (redundant) + register single-scan compaction -----
__global__ __launch_bounds__(256) void kD(const float* __restrict__ mmaxW,
                                          const int* __restrict__ midxW,
                                          const int* __restrict__ pNA,
                                          const u64* __restrict__ rowbits,
                                          const float* __restrict__ points,
                                          float* __restrict__ out,
                                          float* __restrict__ out_anchor)
{
    __shared__ int sA[384];
    __shared__ u32 sl3[256], sl2[256], sl1[256];
    __shared__ u64 swt[13][4];
    int tid = threadIdx.x, bid = blockIdx.x;
    int lane = tid & 63, wv = tid >> 6;

    if (tid < 128) { sA[tid] = -1; sA[tid + 128] = -1; sA[tid + 256] = -1; }
    __syncthreads();
    // ---- packed greedy scan on wave 0 (proven kC2 port): (gof+1)<<16 | cnt, one shfl/iter ----
    if (tid < 64) {
        int NA = *pNA;
        int   mia = midxW[lane], mib = midxW[lane + 64];
        float mxa = mmaxW[lane], mxb = mmaxW[lane + 64];
        int gof1 = -1, gof2 = -1;
        int cnt1 = 0,  cnt2 = 0;
        int ng = 0;
        #pragma unroll 8
        for (int i = 0; i < 128; ++i) {
            int   j  = __shfl((i < 64) ? mia : mib, i & 63);
            float mx = __shfl((i < 64) ? mxa : mxb, i & 63);
            int pk = (j < 64) ? (((gof1 + 1) << 16) | cnt1)
                              : (((gof2 + 1) << 16) | cnt2);
            pk = __shfl(pk, j & 63);           // the ONLY chained cross-lane op
            int gj = (pk >> 16) - 1;
            int gc = pk & 0xffff;
            bool join = (mx > 0.5f) && (gj >= 0) && (gc < NA);
            int tg = join ? gj : ng;
            int ts = join ? gc : 0;
            int ncnt = join ? gc + 1 : 1;
            if (lane == 0) sA[tg * AANCH + ts] = i;
            cnt1 += (gof1 == tg);
            cnt2 += (gof2 == tg);
            if (lane == (i & 63)) {
                if (i < 64) { gof1 = tg; cnt1 = ncnt; }
                else        { gof2 = tg; cnt2 = ncnt; }
            }
            ng += join ? 0 : 1;
        }
    }
    __syncthreads();
    if (bid == 0) {
        for (int t = tid; t < 384; t += 256)
            out_anchor[t] = (float)sA[t];      // int32 ref chunk read back as f32 values
    }
    int g = bid;
    float* outg = out + (size_t)g * SSAMP * 5;
    int a0 = sA[g*3+0], a1 = sA[g*3+1], a2 = sA[g*3+2];
    if (a0 < 0) {                              // invalid group -> all zeros (block-uniform exit)
        for (int t = tid; t < SSAMP * 5; t += 256) outg[t] = 0.0f;
        return;
    }
    bool vB = (a1 >= 0), vC = (a2 >= 0);
    const u64* rA = rowbits + (size_t)a0 * W64C;
    const u64* rB = rowbits + (size_t)(vB ? a1 : 0) * W64C;
    const u64* rC = rowbits + (size_t)(vC ? a2 : 0) * W64C;
    const u64 M21 = (1ull << 21) - 1;

    // ---- prefetch all 13 chunk words (coalesced; one latency hit) ----
    u64 va[13], vb[13], vc[13];
    #pragma unroll
    for (int k = 0; k < 13; ++k) {
        int w = k * 256 + tid;
        bool inr = (w < W64);
        va[k] = inr ? rA[w] : 0ull;
        vb[k] = (inr && vB) ? rB[w] : 0ull;
        vc[k] = (inr && vC) ? rC[w] : 0ull;
    }
    // ---- per-chunk packed counts + 13 independent wave scans (no barriers between) ----
    u64 exl[13];
    #pragma unroll
    for (int k = 0; k < 13; ++k) {
        u64 a = va[k], b = vb[k], c = vc[k];
        u64 m3 = a & b & c;
        u64 any2 = (a & b) | (a & c) | (b & c);
        u64 m2 = any2 & ~m3;
        u64 m1 = (a | b | c) & ~any2;
        u64 own = ((u64)__popcll(m3) << 42) | ((u64)__popcll(m2) << 21) | (u64)__popcll(m1);
        u64 p = own;
        #pragma unroll
        for (int d = 1; d < 64; d <<= 1) {
            u64 t = __shfl_up(p, d);
            if (lane >= d) p += t;
        }
        if (lane == 63) swt[k][wv] = p;
        exl[k] = p - own;
    }
    __syncthreads();
    // ---- per-chunk offsets from wave totals; emit (chunk-major global order) ----
    u64 base = 0;
    #pragma unroll
    for (int k = 0; k < 13; ++k) {
        u64 off = base + exl[k];
        for (int w2 = 0; w2 < wv; ++w2) off += swt[k][w2];
        u64 a = va[k], b = vb[k], c = vc[k];
        u64 m3 = a & b & c;
        u64 any2 = (a & b) | (a & c) | (b & c);
        u64 m2 = any2 & ~m3;
        u64 m1 = (a | b | c) & ~any2;
        u32 e3 = (u32)(off >> 42);
        u32 e2 = (u32)((off >> 21) & M21);
        u32 e1 = (u32)(off & M21);
        int nb = k * 256 * 64 + tid * 64;
        u64 mm = m3; u32 o = e3;
        while (mm) { int b2 = __builtin_ctzll(mm); mm &= mm - 1; if (o < 256) sl3[o] = nb + b2; o++; }
        mm = m2; o = e2;
        while (mm) { int b2 = __builtin_ctzll(mm); mm &= mm - 1; if (o < 256) sl2[o] = nb + b2; o++; }
        mm = m1; o = e1;
        while (mm) { int b2 = __builtin_ctzll(mm); mm &= mm - 1; if (o < 256) sl1[o] = nb + b2; o++; }
        base += swt[k][0] + swt[k][1] + swt[k][2] + swt[k][3];
    }
    __syncthreads();
    u32 t3 = (u32)(base >> 42), t2c = (u32)((base >> 21) & M21), t1 = (u32)(base & M21);
    u32 s = (u32)tid;
    int n = -1;
    if (s < t3)                  n = (int)sl3[s];
    else if (s < t3 + t2c)       n = (int)sl2[s - t3];
    else if (s < t3 + t2c + t1)  n = (int)sl1[s - t3 - t2c];
    float v0=0.f, v1=0.f, v2=0.f, v3=0.f, v4=0.f;
    if (n >= 0) {
        const float* pp = points + (size_t)n * 5;
        v0 = pp[0]; v1 = pp[1]; v2 = pp[2]; v3 = pp[3]; v4 = pp[4];
    }
    outg[s*5+0] = v0; outg[s*5+1] = v1; outg[s*5+2] = v2;
    outg[s*5+3] = v3; outg[s*5+4] = v4;
}

extern "C" void kernel_launch(void* const* d_in, const int* in_sizes, int n_in,
                              void* d_out, int out_size, void* d_ws, size_t ws_size,
                              hipStream_t stream)
{
    const float* points = (const float*)d_in[0];
    const float* boxes  = (const float*)d_in[1];
    const int*   labels = (const int*)d_in[2];
    const int*   pNA    = (const int*)d_in[4];
    float* out = (float*)d_out;
    char* ws = (char*)d_ws;

    size_t rowsz = (size_t)MBOX * W64C * 8;                    // 3,276,800 B
    u64*  rowbits = (u64*)ws;
    u32*  inter   = (u32*)(ws + rowsz);                        // 65,536 B (contiguous zero region)
    float* bpk    = (float*)(ws + rowsz + 65536);              // 4,096 B
    u64*  tmask   = (u64*)(ws + rowsz + 65536 + 4096);         // 4,096 B
    float* mmaxW  = (float*)(ws + rowsz + 65536 + 8192);       // 512 B
    int*   midxW  = (int*)(ws + rowsz + 65536 + 8704);         // 512 B

    float* out_anchor = out + (size_t)MBOX * SSAMP * 5;        // second output chunk

    kZP<<<816, 256, 0, stream>>>((uint4*)ws, boxes, bpk, tmask);
    kA<<<(NPTS + 255) / 256, 256, 0, stream>>>(points, bpk, tmask, rowbits, inter);
    kC1<<<MBOX, 64, 0, stream>>>(inter, labels, mmaxW, midxW);
    kD<<<MBOX, 256, 0, stream>>>(mmaxW, midxW, pNA, rowbits, points, out, out_anchor);
}